// Round 17
// baseline (5344.575 us; speedup 1.0000x reference)
//
#include <hip/hip_runtime.h>

// repack OIHW (fp32) -> [ic*K*K][oc]
template<int OC>
__global__ __launch_bounds__(256) void repack_k(const float* __restrict__ w,
                                                float* __restrict__ wT, int tot) {
  int i = blockIdx.x * 256 + threadIdx.x;
  if (i >= tot) return;
  int row = i / OC, oc = i - row * OC;          // row = ic*K*K + ky*K + kx
  wT[i] = w[(size_t)oc * (size_t)(tot / OC) + row];
}

// e2[r] = sum_f32 e*e
__global__ __launch_bounds__(256) void e2_k(const float* __restrict__ emb,
                                            float* __restrict__ e2) {
  int r = blockIdx.x * 256 + threadIdx.x;
  if (r >= 512) return;
  float s = 0.f;
#pragma unroll
  for (int d = 0; d < 64; ++d) s = fmaf(emb[r * 64 + d], emb[r * 64 + d], s);
  e2[r] = s;
}

// Direct conv, 4-pixel register blocking, spill-free OCH sizing.
// 32x32 output tile, 256 threads, each thread: 4 adjacent-x pixels x OCH chans.
// Weights staged in LDS (slice of [ic*K*K+ky*K+kx][OCTOT]); input tile in LDS.
// Per-output FMA order identical to the 1-pixel version (bit-exact).
template<int IC, int OCTOT, int OCH, int K, int S, int PAD, int CCH,
         int IH, int IW, bool RELU_IN, bool RELU_OUT>
__global__ __launch_bounds__(256, 2) void conv_p4(
    const float* __restrict__ in, const float* __restrict__ wT,
    const float* __restrict__ bias, float* __restrict__ out) {
  constexpr int OH = (IH + 2 * PAD - K) / S + 1;
  constexpr int OW = OH;
  constexpr int TR = 32, TC = 32;          // output tile
  constexpr int RS = (TR - 1) * S + K;     // input rows staged
  constexpr int CSR = (TC - 1) * S + K;    // input cols (real)
  constexpr int CS = (CSR + 3) & ~3;       // padded stride (float4 align)
  constexpr int TX = OW / TC;
  constexpr int TILES = (OH / TR) * TX;
  constexpr int TOT = CCH * RS * CS;
  constexpr int WSLAB = CCH * K * K * OCH;
  constexpr int VW = ((3 * S + K) + 3) & ~3;   // sliding-window floats

  __shared__ __align__(16) float lds[TOT];
  __shared__ __align__(16) float wlds[WSLAB];

  const int tid = threadIdx.x;
  const int n = blockIdx.y;
  const int tile = blockIdx.x % TILES;
  const int oc0 = (blockIdx.x / TILES) * OCH;
  const int oh0 = (tile / TX) * TR;
  const int ow0 = (tile % TX) * TC;
  const int r = tid >> 3;                  // 0..31
  const int c0 = (tid & 7) * 4;            // 0,4,..,28

  float acc[4][OCH];
#pragma unroll
  for (int oc = 0; oc < OCH; ++oc) {
    float b = bias[oc0 + oc];
    acc[0][oc] = b; acc[1][oc] = b; acc[2][oc] = b; acc[3][oc] = b;
  }

  for (int ic0 = 0; ic0 < IC; ic0 += CCH) {
    __syncthreads();
    // stage input tile
    for (int i = tid; i < TOT; i += 256) {
      int c = i / (RS * CS);
      int rem = i - c * (RS * CS);
      int rr = rem / CS;
      int col = rem - rr * CS;
      int gr = oh0 * S + rr - PAD;
      int gc = ow0 * S + col - PAD;
      float v = 0.f;
      if (gr >= 0 && gr < IH && gc >= 0 && gc < IW) {
        v = in[((size_t)(n * IC + ic0 + c) * IH + gr) * IW + gc];
        if (RELU_IN) v = fmaxf(v, 0.f);
      }
      lds[i] = v;
    }
    // stage weight slice (rows of [.][OCTOT] at column offset oc0)
    {
      const float* wsrc = wT + (size_t)ic0 * (K * K * OCTOT) + oc0;
      for (int i = tid; i < WSLAB; i += 256) {
        int row = i / OCH, c = i - row * OCH;
        wlds[i] = wsrc[(size_t)row * OCTOT + c];
      }
    }
    __syncthreads();
#pragma unroll 1
    for (int c = 0; c < CCH; ++c) {
#pragma unroll
      for (int ky = 0; ky < K; ++ky) {
        float vwin[VW];
        const float* vrow = lds + (c * RS + r * S + ky) * CS + c0 * S;
#pragma unroll
        for (int q = 0; q < VW / 4; ++q) {
          float4 t = ((const float4*)vrow)[q];
          vwin[4 * q + 0] = t.x; vwin[4 * q + 1] = t.y;
          vwin[4 * q + 2] = t.z; vwin[4 * q + 3] = t.w;
        }
#pragma unroll
        for (int kx = 0; kx < K; ++kx) {
          const float4* w4 =
              (const float4*)(wlds + (c * K * K + ky * K + kx) * OCH);
#pragma unroll
          for (int q = 0; q < OCH / 4; ++q) {
            float4 wv = w4[q];
#pragma unroll
            for (int p = 0; p < 4; ++p) {
              acc[p][4 * q + 0] = fmaf(wv.x, vwin[p * S + kx], acc[p][4 * q + 0]);
              acc[p][4 * q + 1] = fmaf(wv.y, vwin[p * S + kx], acc[p][4 * q + 1]);
              acc[p][4 * q + 2] = fmaf(wv.z, vwin[p * S + kx], acc[p][4 * q + 2]);
              acc[p][4 * q + 3] = fmaf(wv.w, vwin[p * S + kx], acc[p][4 * q + 3]);
            }
          }
        }
      }
    }
  }

  const int oh = oh0 + r, ow = ow0 + c0;
#pragma unroll
  for (int oc = 0; oc < OCH; ++oc) {
    float4 o;
    o.x = acc[0][oc]; o.y = acc[1][oc]; o.z = acc[2][oc]; o.w = acc[3][oc];
    if (RELU_OUT) {
      o.x = fmaxf(o.x, 0.f); o.y = fmaxf(o.y, 0.f);
      o.z = fmaxf(o.z, 0.f); o.w = fmaxf(o.w, 0.f);
    }
    *(float4*)(out + ((size_t)(n * OCTOT + oc0 + oc) * OH + oh) * OW + ow) = o;
  }
}

// 1x1 conv (relu on read) + residual add; 4 px/thread, OCH-slice per block.
// grid.x = 4 px-blocks * (OCTOT/OCH); spatial = 4096.
template<int IC, int OCTOT, int OCH>
__global__ __launch_bounds__(256, 2) void conv1x1_res_p4(
    const float* __restrict__ in, const float* __restrict__ wT,
    const float* __restrict__ bias, const float* __restrict__ res,
    float* __restrict__ out) {
  __shared__ __align__(16) float wlds[IC * OCH];
  const int tid = threadIdx.x;
  const int n = blockIdx.y;
  const int pxb = blockIdx.x % 4;
  const int oc0 = (blockIdx.x / 4) * OCH;
  for (int i = tid; i < IC * OCH; i += 256) {
    int row = i / OCH, c = i - row * OCH;
    wlds[i] = wT[(size_t)row * OCTOT + oc0 + c];
  }
  __syncthreads();

  const int px = pxb * 1024 + tid * 4;
  float acc[4][OCH];
#pragma unroll
  for (int oc = 0; oc < OCH; ++oc) {
    float b = bias[oc0 + oc];
    acc[0][oc] = b; acc[1][oc] = b; acc[2][oc] = b; acc[3][oc] = b;
  }
#pragma unroll 2
  for (int i = 0; i < IC; ++i) {
    float4 v = *(const float4*)(in + (size_t)(n * IC + i) * 4096 + px);
    v.x = fmaxf(v.x, 0.f); v.y = fmaxf(v.y, 0.f);
    v.z = fmaxf(v.z, 0.f); v.w = fmaxf(v.w, 0.f);
    const float4* w4 = (const float4*)(wlds + i * OCH);
#pragma unroll
    for (int q = 0; q < OCH / 4; ++q) {
      float4 wv = w4[q];
      acc[0][4 * q + 0] = fmaf(wv.x, v.x, acc[0][4 * q + 0]);
      acc[0][4 * q + 1] = fmaf(wv.y, v.x, acc[0][4 * q + 1]);
      acc[0][4 * q + 2] = fmaf(wv.z, v.x, acc[0][4 * q + 2]);
      acc[0][4 * q + 3] = fmaf(wv.w, v.x, acc[0][4 * q + 3]);
      acc[1][4 * q + 0] = fmaf(wv.x, v.y, acc[1][4 * q + 0]);
      acc[1][4 * q + 1] = fmaf(wv.y, v.y, acc[1][4 * q + 1]);
      acc[1][4 * q + 2] = fmaf(wv.z, v.y, acc[1][4 * q + 2]);
      acc[1][4 * q + 3] = fmaf(wv.w, v.y, acc[1][4 * q + 3]);
      acc[2][4 * q + 0] = fmaf(wv.x, v.z, acc[2][4 * q + 0]);
      acc[2][4 * q + 1] = fmaf(wv.y, v.z, acc[2][4 * q + 1]);
      acc[2][4 * q + 2] = fmaf(wv.z, v.z, acc[2][4 * q + 2]);
      acc[2][4 * q + 3] = fmaf(wv.w, v.z, acc[2][4 * q + 3]);
      acc[3][4 * q + 0] = fmaf(wv.x, v.w, acc[3][4 * q + 0]);
      acc[3][4 * q + 1] = fmaf(wv.y, v.w, acc[3][4 * q + 1]);
      acc[3][4 * q + 2] = fmaf(wv.z, v.w, acc[3][4 * q + 2]);
      acc[3][4 * q + 3] = fmaf(wv.w, v.w, acc[3][4 * q + 3]);
    }
  }
#pragma unroll
  for (int oc = 0; oc < OCH; ++oc) {
    const size_t o = (size_t)(n * OCTOT + oc0 + oc) * 4096 + px;
    float4 r4 = *(const float4*)(res + o);
    float4 v;
    v.x = r4.x + acc[0][oc]; v.y = r4.y + acc[1][oc];
    v.z = r4.z + acc[2][oc]; v.w = r4.w + acc[3][oc];
    *(float4*)(out + o) = v;
  }
}

// Fused: relu -> conv4 (1x1, 128->64) -> VQ distances/argmin (fp32)
// -> gather raw fp32 emb row, (B,H,W,D) contiguous.
__global__ __launch_bounds__(256, 2) void conv4_vq(
    const float* __restrict__ h, const float* __restrict__ wT4,
    const float* __restrict__ b4, const float* __restrict__ emb,
    const float* __restrict__ e2, float* __restrict__ out) {
  __shared__ __align__(16) float wlds[128 * 64];   // 32 KB
  __shared__ __align__(16) float elds[64 * 64];    // 16 KB
  __shared__ float e2lds[512];                     // 2 KB

  const int tid = threadIdx.x;
  for (int i = tid; i < 128 * 64; i += 256) wlds[i] = wT4[i];
  for (int i = tid; i < 512; i += 256) e2lds[i] = e2[i];
  __syncthreads();

  const int pid = blockIdx.x * 256 + tid;
  const int n = pid >> 12, px = pid & 4095;
  const float* ip = h + (size_t)n * 128 * 4096 + px;
  float z[64];
#pragma unroll
  for (int d = 0; d < 64; ++d) z[d] = b4[d];
#pragma unroll 2
  for (int i = 0; i < 128; ++i) {
    float v = fmaxf(ip[(size_t)i * 4096], 0.f);
    const float4* w4 = (const float4*)(wlds + i * 64);
#pragma unroll
    for (int q = 0; q < 16; ++q) {
      float4 wv = w4[q];
      z[4 * q + 0] = fmaf(wv.x, v, z[4 * q + 0]);
      z[4 * q + 1] = fmaf(wv.y, v, z[4 * q + 1]);
      z[4 * q + 2] = fmaf(wv.z, v, z[4 * q + 2]);
      z[4 * q + 3] = fmaf(wv.w, v, z[4 * q + 3]);
    }
  }
  float z2 = 0.f;
#pragma unroll
  for (int d = 0; d < 64; ++d) z2 = fmaf(z[d], z[d], z2);

  float best = __builtin_inff();
  int bidx = 0;
  for (int r0 = 0; r0 < 512; r0 += 64) {
    __syncthreads();
    for (int i = tid; i < 64 * 64; i += 256) elds[i] = emb[(size_t)r0 * 64 + i];
    __syncthreads();
#pragma unroll 1
    for (int r = 0; r < 64; ++r) {
      const float4* e4 = (const float4*)(elds + r * 64);
      float p0 = 0.f, p1 = 0.f, p2 = 0.f, p3 = 0.f;
#pragma unroll
      for (int q = 0; q < 16; ++q) {
        float4 ev = e4[q];
        p0 = fmaf(ev.x, z[4 * q + 0], p0);
        p1 = fmaf(ev.y, z[4 * q + 1], p1);
        p2 = fmaf(ev.z, z[4 * q + 2], p2);
        p3 = fmaf(ev.w, z[4 * q + 3], p3);
      }
      float dot = (p0 + p1) + (p2 + p3);
      float dist = (z2 - 2.f * dot) + e2lds[r0 + r];  // ref association order
      if (dist < best) { best = dist; bidx = r0 + r; }  // strict <, 1st index
    }
  }

  // (B,H,W,D) contiguous gather: out[pid*64 + d] = emb[bidx][d], fp32 verbatim
  const float4* eb = (const float4*)(emb + (size_t)bidx * 64);
  float4* op = (float4*)(out + (size_t)pid * 64);
#pragma unroll
  for (int q = 0; q < 16; ++q) op[q] = eb[q];
}

extern "C" void kernel_launch(void* const* d_in, const int* in_sizes, int n_in,
                              void* d_out, int out_size, void* d_ws, size_t ws_size,
                              hipStream_t stream) {
  const float* x    = (const float*)d_in[0];
  const float* w1   = (const float*)d_in[1];
  const float* b1   = (const float*)d_in[2];
  const float* w2   = (const float*)d_in[3];
  const float* b2   = (const float*)d_in[4];
  const float* w3   = (const float*)d_in[5];
  const float* b3   = (const float*)d_in[6];
  const float* r1w1 = (const float*)d_in[7];
  const float* r1b1 = (const float*)d_in[8];
  const float* r1w2 = (const float*)d_in[9];
  const float* r1b2 = (const float*)d_in[10];
  const float* r2w1 = (const float*)d_in[11];
  const float* r2b1 = (const float*)d_in[12];
  const float* r2w2 = (const float*)d_in[13];
  const float* r2b2 = (const float*)d_in[14];
  const float* w4   = (const float*)d_in[15];
  const float* b4   = (const float*)d_in[16];
  const float* emb  = (const float*)d_in[17];

  // ---- workspace: f32 weights up front, f32 activations per batch chunk ----
  char* ws = (char*)d_ws;
  float* wT1   = (float*)ws;         // 1024
  float* wT2   = wT1 + 1024;         // 131072
  float* wT3   = wT2 + 131072;       // 147456
  float* wTr1a = wT3 + 147456;       // 36864
  float* wTr1b = wTr1a + 36864;      // 4096
  float* wTr2a = wTr1b + 4096;       // 36864
  float* wTr2b = wTr2a + 36864;      // 4096
  float* wT4   = wTr2b + 4096;       // 8192
  float* e2v   = wT4 + 8192;         // 512

  const size_t WOFF = 2ull << 20;                  // 2 MiB for weights
  const size_t SZ_A = 4194304ull;    // per-image: 64ch*128*128*4 (h1/h3/h5)
  const size_t SZ_B = 2097152ull;    // per-image: 128ch*64*64*4  (h2/h4)
  const size_t SZ_C = 524288ull;     // per-image: 32ch*64*64*4   (t32)
  const size_t PER_IMG = SZ_A + SZ_B + SZ_C;       // 6.5 MiB
  int NB = 64;
  while (NB > 1 && WOFF + (size_t)NB * PER_IMG > ws_size) NB >>= 1;

  char* bufs = ws + WOFF;
  float* A  = (float*)bufs;
  float* B_ = (float*)(bufs + (size_t)NB * SZ_A);
  float* C_ = (float*)(bufs + (size_t)NB * (SZ_A + SZ_B));

  auto blk = [](int tot) { return (tot + 255) / 256; };
  repack_k<64> <<<blk(1024),   256, 0, stream>>>(w1,   wT1,   1024);
  repack_k<128><<<blk(131072), 256, 0, stream>>>(w2,   wT2,   131072);
  repack_k<128><<<blk(147456), 256, 0, stream>>>(w3,   wT3,   147456);
  repack_k<32> <<<blk(36864),  256, 0, stream>>>(r1w1, wTr1a, 36864);
  repack_k<128><<<blk(4096),   256, 0, stream>>>(r1w2, wTr1b, 4096);
  repack_k<32> <<<blk(36864),  256, 0, stream>>>(r2w1, wTr2a, 36864);
  repack_k<128><<<blk(4096),   256, 0, stream>>>(r2w2, wTr2b, 4096);
  repack_k<64> <<<blk(8192),   256, 0, stream>>>(w4,   wT4,   8192);
  e2_k<<<2, 256, 0, stream>>>(emb, e2v);

  for (int n0 = 0; n0 < 64; n0 += NB) {
    const int nb = (64 - n0 < NB) ? (64 - n0) : NB;
    const float* xc = x + (size_t)n0 * 65536;               // (nb,1,256,256)
    float* oc = (float*)d_out + (size_t)n0 * 4096 * 64;     // BHWD chunk base

    // conv1: (nb,1,256,256) -> relu -> h1; 16 tiles x 4 slices (OCH=16)
    conv_p4<1, 64, 16, 4, 2, 1, 1, 256, 256, false, true>
        <<<dim3(64, nb), 256, 0, stream>>>(xc, wT1, b1, A);
    // conv2: h1 -> relu -> h2; 4 tiles x 8 slices (OCH=16)
    conv_p4<64, 128, 16, 4, 2, 1, 2, 128, 128, false, true>
        <<<dim3(32, nb), 256, 0, stream>>>(A, wT2, b2, B_);
    // conv3: h2 -> h3; 4 tiles x 8 slices (OCH=16)
    conv_p4<128, 128, 16, 3, 1, 1, 4, 64, 64, false, false>
        <<<dim3(32, nb), 256, 0, stream>>>(B_, wT3, b3, A);
    // res1: t32 = conv3x3(relu(h3)); 4 tiles x 4 slices (OCH=8)
    conv_p4<128, 32, 8, 3, 1, 1, 8, 64, 64, true, false>
        <<<dim3(16, nb), 256, 0, stream>>>(A, wTr1a, r1b1, C_);
    conv1x1_res_p4<32, 128, 16><<<dim3(32, nb), 256, 0, stream>>>(
        C_, wTr1b, r1b2, A, B_);
    // res2: t32 = conv3x3(relu(h4)); h5 = h4 + conv1x1(relu(t32))
    conv_p4<128, 32, 8, 3, 1, 1, 8, 64, 64, true, false>
        <<<dim3(16, nb), 256, 0, stream>>>(B_, wTr2a, r2b1, C_);
    conv1x1_res_p4<32, 128, 16><<<dim3(32, nb), 256, 0, stream>>>(
        C_, wTr2b, r2b2, B_, A);
    // conv4 + VQ: relu(h5) -> z (fp32) -> fp32 distances -> argmin
    //  -> gather raw fp32 emb row, (B,H,W,D) contiguous
    conv4_vq<<<nb * 16, 256, 0, stream>>>(A, wT4, b4, emb, e2v, oc);
  }
}

// Round 18
// 4338.906 us; speedup vs baseline: 1.2318x; 1.2318x over previous
//
#include <hip/hip_runtime.h>

#define TDIM 16

// repack OIHW (fp32) -> [ic*K*K][oc]
template<int OC>
__global__ __launch_bounds__(256) void repack_k(const float* __restrict__ w,
                                                float* __restrict__ wT, int tot) {
  int i = blockIdx.x * 256 + threadIdx.x;
  if (i >= tot) return;
  int row = i / OC, oc = i - row * OC;          // row = ic*K*K + ky*K + kx
  wT[i] = w[(size_t)oc * (size_t)(tot / OC) + row];
}

// e2[r] = sum_f32 e*e
__global__ __launch_bounds__(256) void e2_k(const float* __restrict__ emb,
                                            float* __restrict__ e2) {
  int r = blockIdx.x * 256 + threadIdx.x;
  if (r >= 512) return;
  float s = 0.f;
#pragma unroll
  for (int d = 0; d < 64; ++d) s = fmaf(emb[r * 64 + d], emb[r * 64 + d], s);
  e2[r] = s;
}

// 1-px direct conv (R14/R15-proven): fp32, bias in acc, LDS weights.
// Computes OCH of OCTOT channels; TDIM x TDIM tile, 256 threads.
template<int IC, int OCTOT, int OCH, int K, int S, int PAD, int CCH,
         int IH, int IW, bool RELU_IN, bool RELU_OUT>
__global__ __launch_bounds__(256) void conv_direct(
    const float* __restrict__ in, const float* __restrict__ wT,
    const float* __restrict__ bias, float* __restrict__ out) {
  constexpr int OH = (IH + 2 * PAD - K) / S + 1;
  constexpr int OW = OH;
  constexpr int RS = (TDIM - 1) * S + K;
  constexpr int CS = RS;
  constexpr int TX = OW / TDIM;
  constexpr int TILES = TX * TX;
  constexpr int TOT = CCH * RS * CS;
  constexpr int WSLAB = CCH * K * K * OCH;

  __shared__ __align__(16) float lds[TOT];
  __shared__ __align__(16) float wlds[WSLAB];

  const int tid = threadIdx.x;
  const int n = blockIdx.y;
  const int tile = blockIdx.x % TILES;
  const int oc0 = (blockIdx.x / TILES) * OCH;
  const int oh0 = (tile / TX) * TDIM;
  const int ow0 = (tile % TX) * TDIM;
  const int ty = tid >> 4, tx = tid & 15;
  const int oh = oh0 + ty, ow = ow0 + tx;

  float acc[OCH];
#pragma unroll
  for (int oc = 0; oc < OCH; ++oc) acc[oc] = bias[oc0 + oc];

  for (int ic0 = 0; ic0 < IC; ic0 += CCH) {
    __syncthreads();
    for (int i = tid; i < TOT; i += 256) {
      int c = i / (RS * CS);
      int rem = i - c * (RS * CS);
      int r = rem / CS;
      int col = rem - r * CS;
      int gr = oh0 * S + r - PAD;
      int gc = ow0 * S + col - PAD;
      float v = 0.f;
      if (gr >= 0 && gr < IH && gc >= 0 && gc < IW) {
        v = in[((size_t)(n * IC + ic0 + c) * IH + gr) * IW + gc];
        if (RELU_IN) v = fmaxf(v, 0.f);
      }
      lds[i] = v;
    }
    {
      const float* wsrc = wT + (size_t)ic0 * (K * K * OCTOT) + oc0;
      for (int i = tid; i < WSLAB; i += 256) {
        int row = i / OCH, c = i - row * OCH;
        wlds[i] = wsrc[(size_t)row * OCTOT + c];
      }
    }
    __syncthreads();
#pragma unroll 1
    for (int c = 0; c < CCH; ++c) {
#pragma unroll
      for (int ky = 0; ky < K; ++ky)
#pragma unroll
        for (int kx = 0; kx < K; ++kx) {
          float v = lds[(c * RS + ty * S + ky) * CS + tx * S + kx];
          const float4* w4 =
              (const float4*)(wlds + (c * K * K + ky * K + kx) * OCH);
#pragma unroll
          for (int q = 0; q < OCH / 4; ++q) {
            float4 wv = w4[q];
            acc[4 * q + 0] = fmaf(wv.x, v, acc[4 * q + 0]);
            acc[4 * q + 1] = fmaf(wv.y, v, acc[4 * q + 1]);
            acc[4 * q + 2] = fmaf(wv.z, v, acc[4 * q + 2]);
            acc[4 * q + 3] = fmaf(wv.w, v, acc[4 * q + 3]);
          }
        }
    }
  }

#pragma unroll
  for (int oc = 0; oc < OCH; ++oc) {
    float r = acc[oc];
    if (RELU_OUT) r = fmaxf(r, 0.f);
    out[((size_t)(n * OCTOT + oc0 + oc) * OH + oh) * OW + ow] = r;
  }
}

// 4-px register-blocked conv (R16/R17-proven correctness), launch_bounds(256,1)
// to give the register allocator a 512-VGPR budget (keep acc out of AGPRs).
// 32x32 output tile, 256 threads, 4 adjacent-x px x OCH chans per thread.
template<int IC, int OCTOT, int OCH, int K, int S, int PAD, int CCH,
         int IH, int IW, bool RELU_IN, bool RELU_OUT>
__global__ __launch_bounds__(256, 1) void conv_p4(
    const float* __restrict__ in, const float* __restrict__ wT,
    const float* __restrict__ bias, float* __restrict__ out) {
  constexpr int OH = (IH + 2 * PAD - K) / S + 1;
  constexpr int OW = OH;
  constexpr int TR = 32, TC = 32;
  constexpr int RS = (TR - 1) * S + K;
  constexpr int CSR = (TC - 1) * S + K;
  constexpr int CS = (CSR + 3) & ~3;
  constexpr int TX = OW / TC;
  constexpr int TILES = (OH / TR) * TX;
  constexpr int TOT = CCH * RS * CS;
  constexpr int WSLAB = CCH * K * K * OCH;
  constexpr int VW = ((3 * S + K) + 3) & ~3;

  __shared__ __align__(16) float lds[TOT];
  __shared__ __align__(16) float wlds[WSLAB];

  const int tid = threadIdx.x;
  const int n = blockIdx.y;
  const int tile = blockIdx.x % TILES;
  const int oc0 = (blockIdx.x / TILES) * OCH;
  const int oh0 = (tile / TX) * TR;
  const int ow0 = (tile % TX) * TC;
  const int r = tid >> 3;
  const int c0 = (tid & 7) * 4;

  float acc[4][OCH];
#pragma unroll
  for (int oc = 0; oc < OCH; ++oc) {
    float b = bias[oc0 + oc];
    acc[0][oc] = b; acc[1][oc] = b; acc[2][oc] = b; acc[3][oc] = b;
  }

  for (int ic0 = 0; ic0 < IC; ic0 += CCH) {
    __syncthreads();
    for (int i = tid; i < TOT; i += 256) {
      int c = i / (RS * CS);
      int rem = i - c * (RS * CS);
      int rr = rem / CS;
      int col = rem - rr * CS;
      int gr = oh0 * S + rr - PAD;
      int gc = ow0 * S + col - PAD;
      float v = 0.f;
      if (gr >= 0 && gr < IH && gc >= 0 && gc < IW) {
        v = in[((size_t)(n * IC + ic0 + c) * IH + gr) * IW + gc];
        if (RELU_IN) v = fmaxf(v, 0.f);
      }
      lds[i] = v;
    }
    {
      const float* wsrc = wT + (size_t)ic0 * (K * K * OCTOT) + oc0;
      for (int i = tid; i < WSLAB; i += 256) {
        int row = i / OCH, c = i - row * OCH;
        wlds[i] = wsrc[(size_t)row * OCTOT + c];
      }
    }
    __syncthreads();
#pragma unroll 1
    for (int c = 0; c < CCH; ++c) {
#pragma unroll
      for (int ky = 0; ky < K; ++ky) {
        float vwin[VW];
        const float* vrow = lds + (c * RS + r * S + ky) * CS + c0 * S;
#pragma unroll
        for (int q = 0; q < VW / 4; ++q) {
          float4 t = ((const float4*)vrow)[q];
          vwin[4 * q + 0] = t.x; vwin[4 * q + 1] = t.y;
          vwin[4 * q + 2] = t.z; vwin[4 * q + 3] = t.w;
        }
#pragma unroll
        for (int kx = 0; kx < K; ++kx) {
          const float4* w4 =
              (const float4*)(wlds + (c * K * K + ky * K + kx) * OCH);
#pragma unroll
          for (int q = 0; q < OCH / 4; ++q) {
            float4 wv = w4[q];
#pragma unroll
            for (int p = 0; p < 4; ++p) {
              acc[p][4 * q + 0] = fmaf(wv.x, vwin[p * S + kx], acc[p][4 * q + 0]);
              acc[p][4 * q + 1] = fmaf(wv.y, vwin[p * S + kx], acc[p][4 * q + 1]);
              acc[p][4 * q + 2] = fmaf(wv.z, vwin[p * S + kx], acc[p][4 * q + 2]);
              acc[p][4 * q + 3] = fmaf(wv.w, vwin[p * S + kx], acc[p][4 * q + 3]);
            }
          }
        }
      }
    }
  }

  const int oh = oh0 + r, ow = ow0 + c0;
#pragma unroll
  for (int oc = 0; oc < OCH; ++oc) {
    float4 o;
    o.x = acc[0][oc]; o.y = acc[1][oc]; o.z = acc[2][oc]; o.w = acc[3][oc];
    if (RELU_OUT) {
      o.x = fmaxf(o.x, 0.f); o.y = fmaxf(o.y, 0.f);
      o.z = fmaxf(o.z, 0.f); o.w = fmaxf(o.w, 0.f);
    }
    *(float4*)(out + ((size_t)(n * OCTOT + oc0 + oc) * OH + oh) * OW + ow) = o;
  }
}

// 1x1 conv (relu on read) + residual add, fp32; weights staged in LDS. (R14)
template<int IC, int OC>
__global__ __launch_bounds__(256) void conv1x1_res(
    const float* __restrict__ in, const float* __restrict__ wT,
    const float* __restrict__ bias, const float* __restrict__ res,
    float* __restrict__ out) {
  __shared__ __align__(16) float wlds[IC * OC];
  for (int i = threadIdx.x; i < IC * OC; i += 256) wlds[i] = wT[i];
  __syncthreads();

  const int pid = blockIdx.x * 256 + threadIdx.x;
  const int n = pid >> 12, px = pid & 4095;
  const float* ip = in + (size_t)n * IC * 4096 + px;
  float acc[OC];
#pragma unroll
  for (int o = 0; o < OC; ++o) acc[o] = bias[o];
#pragma unroll 4
  for (int i = 0; i < IC; ++i) {
    float v = fmaxf(ip[(size_t)i * 4096], 0.f);
    const float4* w4 = (const float4*)(wlds + i * OC);
#pragma unroll
    for (int q = 0; q < OC / 4; ++q) {
      float4 wv = w4[q];
      acc[4 * q + 0] = fmaf(wv.x, v, acc[4 * q + 0]);
      acc[4 * q + 1] = fmaf(wv.y, v, acc[4 * q + 1]);
      acc[4 * q + 2] = fmaf(wv.z, v, acc[4 * q + 2]);
      acc[4 * q + 3] = fmaf(wv.w, v, acc[4 * q + 3]);
    }
  }
  const float* rp = res + (size_t)n * OC * 4096 + px;
  float* op = out + (size_t)n * OC * 4096 + px;
#pragma unroll
  for (int o = 0; o < OC; ++o) op[(size_t)o * 4096] = rp[(size_t)o * 4096] + acc[o];
}

// Fused conv4 + VQ (R14). LDS-staged wT4/e2/emb-chunks; BHWD gather.
__global__ __launch_bounds__(256) void conv4_vq(
    const float* __restrict__ h, const float* __restrict__ wT4,
    const float* __restrict__ b4, const float* __restrict__ emb,
    const float* __restrict__ e2, float* __restrict__ out) {
  __shared__ __align__(16) float wlds[128 * 64];
  __shared__ __align__(16) float elds[64 * 64];
  __shared__ float e2lds[512];

  const int tid = threadIdx.x;
  for (int i = tid; i < 128 * 64; i += 256) wlds[i] = wT4[i];
  for (int i = tid; i < 512; i += 256) e2lds[i] = e2[i];
  __syncthreads();

  const int pid = blockIdx.x * 256 + tid;
  const int n = pid >> 12, px = pid & 4095;
  const float* ip = h + (size_t)n * 128 * 4096 + px;
  float z[64];
#pragma unroll
  for (int d = 0; d < 64; ++d) z[d] = b4[d];
#pragma unroll 2
  for (int i = 0; i < 128; ++i) {
    float v = fmaxf(ip[(size_t)i * 4096], 0.f);
    const float4* w4 = (const float4*)(wlds + i * 64);
#pragma unroll
    for (int q = 0; q < 16; ++q) {
      float4 wv = w4[q];
      z[4 * q + 0] = fmaf(wv.x, v, z[4 * q + 0]);
      z[4 * q + 1] = fmaf(wv.y, v, z[4 * q + 1]);
      z[4 * q + 2] = fmaf(wv.z, v, z[4 * q + 2]);
      z[4 * q + 3] = fmaf(wv.w, v, z[4 * q + 3]);
    }
  }
  float z2 = 0.f;
#pragma unroll
  for (int d = 0; d < 64; ++d) z2 = fmaf(z[d], z[d], z2);

  float best = __builtin_inff();
  int bidx = 0;
  for (int r0 = 0; r0 < 512; r0 += 64) {
    __syncthreads();
    for (int i = tid; i < 64 * 64; i += 256) elds[i] = emb[(size_t)r0 * 64 + i];
    __syncthreads();
#pragma unroll 1
    for (int r = 0; r < 64; ++r) {
      const float4* e4 = (const float4*)(elds + r * 64);
      float p0 = 0.f, p1 = 0.f, p2 = 0.f, p3 = 0.f;
#pragma unroll
      for (int q = 0; q < 16; ++q) {
        float4 ev = e4[q];
        p0 = fmaf(ev.x, z[4 * q + 0], p0);
        p1 = fmaf(ev.y, z[4 * q + 1], p1);
        p2 = fmaf(ev.z, z[4 * q + 2], p2);
        p3 = fmaf(ev.w, z[4 * q + 3], p3);
      }
      float dot = (p0 + p1) + (p2 + p3);
      float dist = (z2 - 2.f * dot) + e2lds[r0 + r];
      if (dist < best) { best = dist; bidx = r0 + r; }
    }
  }

  const float4* eb = (const float4*)(emb + (size_t)bidx * 64);
  float4* op = (float4*)(out + (size_t)pid * 64);
#pragma unroll
  for (int q = 0; q < 16; ++q) op[q] = eb[q];
}

extern "C" void kernel_launch(void* const* d_in, const int* in_sizes, int n_in,
                              void* d_out, int out_size, void* d_ws, size_t ws_size,
                              hipStream_t stream) {
  const float* x    = (const float*)d_in[0];
  const float* w1   = (const float*)d_in[1];
  const float* b1   = (const float*)d_in[2];
  const float* w2   = (const float*)d_in[3];
  const float* b2   = (const float*)d_in[4];
  const float* w3   = (const float*)d_in[5];
  const float* b3   = (const float*)d_in[6];
  const float* r1w1 = (const float*)d_in[7];
  const float* r1b1 = (const float*)d_in[8];
  const float* r1w2 = (const float*)d_in[9];
  const float* r1b2 = (const float*)d_in[10];
  const float* r2w1 = (const float*)d_in[11];
  const float* r2b1 = (const float*)d_in[12];
  const float* r2w2 = (const float*)d_in[13];
  const float* r2b2 = (const float*)d_in[14];
  const float* w4   = (const float*)d_in[15];
  const float* b4   = (const float*)d_in[16];
  const float* emb  = (const float*)d_in[17];

  char* ws = (char*)d_ws;
  float* wT1   = (float*)ws;         // 1024
  float* wT2   = wT1 + 1024;         // 131072
  float* wT3   = wT2 + 131072;       // 147456
  float* wTr1a = wT3 + 147456;       // 36864
  float* wTr1b = wTr1a + 36864;      // 4096
  float* wTr2a = wTr1b + 4096;       // 36864
  float* wTr2b = wTr2a + 36864;      // 4096
  float* wT4   = wTr2b + 4096;       // 8192
  float* e2v   = wT4 + 8192;         // 512

  const size_t WOFF = 2ull << 20;
  const size_t SZ_A = 4194304ull;    // 64ch*128*128*4 (h1/h3/h5)
  const size_t SZ_B = 2097152ull;    // 128ch*64*64*4  (h2/h4)
  const size_t SZ_C = 524288ull;     // 32ch*64*64*4   (t32)
  const size_t PER_IMG = SZ_A + SZ_B + SZ_C;
  int NB = 64;
  while (NB > 1 && WOFF + (size_t)NB * PER_IMG > ws_size) NB >>= 1;

  char* bufs = ws + WOFF;
  float* A  = (float*)bufs;
  float* B_ = (float*)(bufs + (size_t)NB * SZ_A);
  float* C_ = (float*)(bufs + (size_t)NB * (SZ_A + SZ_B));

  auto blk = [](int tot) { return (tot + 255) / 256; };
  repack_k<64> <<<blk(1024),   256, 0, stream>>>(w1,   wT1,   1024);
  repack_k<128><<<blk(131072), 256, 0, stream>>>(w2,   wT2,   131072);
  repack_k<128><<<blk(147456), 256, 0, stream>>>(w3,   wT3,   147456);
  repack_k<32> <<<blk(36864),  256, 0, stream>>>(r1w1, wTr1a, 36864);
  repack_k<128><<<blk(4096),   256, 0, stream>>>(r1w2, wTr1b, 4096);
  repack_k<32> <<<blk(36864),  256, 0, stream>>>(r2w1, wTr2a, 36864);
  repack_k<128><<<blk(4096),   256, 0, stream>>>(r2w2, wTr2b, 4096);
  repack_k<64> <<<blk(8192),   256, 0, stream>>>(w4,   wT4,   8192);
  e2_k<<<2, 256, 0, stream>>>(emb, e2v);

  for (int n0 = 0; n0 < 64; n0 += NB) {
    const int nb = (64 - n0 < NB) ? (64 - n0) : NB;
    const float* xc = x + (size_t)n0 * 65536;               // (nb,1,256,256)
    float* oc = (float*)d_out + (size_t)n0 * 4096 * 64;     // BHWD chunk base

    // conv1: 1px, OC=64 whole (R14 config)
    conv_direct<1, 64, 64, 4, 2, 1, 1, 256, 256, false, true>
        <<<dim3(64, nb), 256, 0, stream>>>(xc, wT1, b1, A);
    // conv2: 4px, OCH=32, lb(256,1); 4 tiles x 4 slices
    conv_p4<64, 128, 32, 4, 2, 1, 2, 128, 128, false, true>
        <<<dim3(16, nb), 256, 0, stream>>>(A, wT2, b2, B_);
    // conv3: 4px, OCH=32, lb(256,1), CCH=8; 4 tiles x 4 slices
    conv_p4<128, 128, 32, 3, 1, 1, 8, 64, 64, false, false>
        <<<dim3(16, nb), 256, 0, stream>>>(B_, wT3, b3, A);
    // res1: 1px, OC=32 whole, CCH=8 (R14 config)
    conv_direct<128, 32, 32, 3, 1, 1, 8, 64, 64, true, false>
        <<<dim3(16, nb), 256, 0, stream>>>(A, wTr1a, r1b1, C_);
    conv1x1_res<32, 128><<<nb * 16, 256, 0, stream>>>(C_, wTr1b, r1b2, A, B_);
    // res2
    conv_direct<128, 32, 32, 3, 1, 1, 8, 64, 64, true, false>
        <<<dim3(16, nb), 256, 0, stream>>>(B_, wTr2a, r2b1, C_);
    conv1x1_res<32, 128><<<nb * 16, 256, 0, stream>>>(C_, wTr2b, r2b2, B_, A);
    // conv4 + VQ
    conv4_vq<<<nb * 16, 256, 0, stream>>>(A, wT4, b4, emb, e2v, oc);
  }
}

// Round 19
// 4294.774 us; speedup vs baseline: 1.2444x; 1.0103x over previous
//
#include <hip/hip_runtime.h>

#define TDIM 16

// repack OIHW (fp32) -> [ic*K*K][oc]
template<int OC>
__global__ __launch_bounds__(256) void repack_k(const float* __restrict__ w,
                                                float* __restrict__ wT, int tot) {
  int i = blockIdx.x * 256 + threadIdx.x;
  if (i >= tot) return;
  int row = i / OC, oc = i - row * OC;          // row = ic*K*K + ky*K + kx
  wT[i] = w[(size_t)oc * (size_t)(tot / OC) + row];
}

// e2[r] = sum_f32 e*e
__global__ __launch_bounds__(256) void e2_k(const float* __restrict__ emb,
                                            float* __restrict__ e2) {
  int r = blockIdx.x * 256 + threadIdx.x;
  if (r >= 512) return;
  float s = 0.f;
#pragma unroll
  for (int d = 0; d < 64; ++d) s = fmaf(emb[r * 64 + d], emb[r * 64 + d], s);
  e2[r] = s;
}

// 1-px direct conv (R14-proven): fp32, bias in acc, LDS weights.
template<int IC, int OCTOT, int OCH, int K, int S, int PAD, int CCH,
         int IH, int IW, bool RELU_IN, bool RELU_OUT>
__global__ __launch_bounds__(256) void conv_direct(
    const float* __restrict__ in, const float* __restrict__ wT,
    const float* __restrict__ bias, float* __restrict__ out) {
  constexpr int OH = (IH + 2 * PAD - K) / S + 1;
  constexpr int OW = OH;
  constexpr int RS = (TDIM - 1) * S + K;
  constexpr int CS = RS;
  constexpr int TX = OW / TDIM;
  constexpr int TILES = TX * TX;
  constexpr int TOT = CCH * RS * CS;
  constexpr int WSLAB = CCH * K * K * OCH;

  __shared__ __align__(16) float lds[TOT];
  __shared__ __align__(16) float wlds[WSLAB];

  const int tid = threadIdx.x;
  const int n = blockIdx.y;
  const int tile = blockIdx.x % TILES;
  const int oc0 = (blockIdx.x / TILES) * OCH;
  const int oh0 = (tile / TX) * TDIM;
  const int ow0 = (tile % TX) * TDIM;
  const int ty = tid >> 4, tx = tid & 15;
  const int oh = oh0 + ty, ow = ow0 + tx;

  float acc[OCH];
#pragma unroll
  for (int oc = 0; oc < OCH; ++oc) acc[oc] = bias[oc0 + oc];

  for (int ic0 = 0; ic0 < IC; ic0 += CCH) {
    __syncthreads();
    for (int i = tid; i < TOT; i += 256) {
      int c = i / (RS * CS);
      int rem = i - c * (RS * CS);
      int r = rem / CS;
      int col = rem - r * CS;
      int gr = oh0 * S + r - PAD;
      int gc = ow0 * S + col - PAD;
      float v = 0.f;
      if (gr >= 0 && gr < IH && gc >= 0 && gc < IW) {
        v = in[((size_t)(n * IC + ic0 + c) * IH + gr) * IW + gc];
        if (RELU_IN) v = fmaxf(v, 0.f);
      }
      lds[i] = v;
    }
    {
      const float* wsrc = wT + (size_t)ic0 * (K * K * OCTOT) + oc0;
      for (int i = tid; i < WSLAB; i += 256) {
        int row = i / OCH, c = i - row * OCH;
        wlds[i] = wsrc[(size_t)row * OCTOT + c];
      }
    }
    __syncthreads();
#pragma unroll 1
    for (int c = 0; c < CCH; ++c) {
#pragma unroll
      for (int ky = 0; ky < K; ++ky)
#pragma unroll
        for (int kx = 0; kx < K; ++kx) {
          float v = lds[(c * RS + ty * S + ky) * CS + tx * S + kx];
          const float4* w4 =
              (const float4*)(wlds + (c * K * K + ky * K + kx) * OCH);
#pragma unroll
          for (int q = 0; q < OCH / 4; ++q) {
            float4 wv = w4[q];
            acc[4 * q + 0] = fmaf(wv.x, v, acc[4 * q + 0]);
            acc[4 * q + 1] = fmaf(wv.y, v, acc[4 * q + 1]);
            acc[4 * q + 2] = fmaf(wv.z, v, acc[4 * q + 2]);
            acc[4 * q + 3] = fmaf(wv.w, v, acc[4 * q + 3]);
          }
        }
    }
  }

#pragma unroll
  for (int oc = 0; oc < OCH; ++oc) {
    float r = acc[oc];
    if (RELU_OUT) r = fmaxf(r, 0.f);
    out[((size_t)(n * OCTOT + oc0 + oc) * OH + oh) * OW + ow] = r;
  }
}

// 4-px register-blocked conv with T14 async staging + LDS double buffer:
// issue chunk k+1 global loads to REGISTERS, compute chunk k, then ds_write,
// one barrier per chunk. Staged values and per-output FMA order unchanged.
template<int IC, int OCTOT, int OCH, int K, int S, int PAD, int CCH,
         int IH, int IW, bool RELU_IN, bool RELU_OUT>
__global__ __launch_bounds__(256, 1) void conv_p4db(
    const float* __restrict__ in, const float* __restrict__ wT,
    const float* __restrict__ bias, float* __restrict__ out) {
  constexpr int OH = (IH + 2 * PAD - K) / S + 1;
  constexpr int OW = OH;
  constexpr int TR = 32, TC = 32;
  constexpr int RS = (TR - 1) * S + K;
  constexpr int CSR = (TC - 1) * S + K;
  constexpr int CS = (CSR + 3) & ~3;
  constexpr int TX = OW / TC;
  constexpr int TILES = (OH / TR) * TX;
  constexpr int TOT = CCH * RS * CS;
  constexpr int NSTG = (TOT + 255) / 256;
  constexpr int WSLAB = CCH * K * K * OCH;
  constexpr int NWST = (WSLAB + 255) / 256;
  constexpr int NCH = IC / CCH;
  constexpr int VW = ((3 * S + K) + 3) & ~3;

  __shared__ __align__(16) float lds[2][TOT];
  __shared__ __align__(16) float wlds[2][WSLAB];

  const int tid = threadIdx.x;
  const int n = blockIdx.y;
  const int tile = blockIdx.x % TILES;
  const int oc0 = (blockIdx.x / TILES) * OCH;
  const int oh0 = (tile / TX) * TR;
  const int ow0 = (tile % TX) * TC;
  const int r = tid >> 3;
  const int c0 = (tid & 7) * 4;

  float acc[4][OCH];
#pragma unroll
  for (int oc = 0; oc < OCH; ++oc) {
    float b = bias[oc0 + oc];
    acc[0][oc] = b; acc[1][oc] = b; acc[2][oc] = b; acc[3][oc] = b;
  }

  float tmp[NSTG];
  float wtmp[NWST];

  auto loadc = [&](int ic0) {
#pragma unroll
    for (int s = 0; s < NSTG; ++s) {
      int i = s * 256 + tid;
      float v = 0.f;
      if (i < TOT) {
        int cc = i / (RS * CS);
        int rem = i - cc * (RS * CS);
        int rr = rem / CS;
        int col = rem - rr * CS;
        int gr = oh0 * S + rr - PAD;
        int gc = ow0 * S + col - PAD;
        if (gr >= 0 && gr < IH && gc >= 0 && gc < IW) {
          v = in[((size_t)(n * IC + ic0 + cc) * IH + gr) * IW + gc];
          if (RELU_IN) v = fmaxf(v, 0.f);
        }
      }
      tmp[s] = v;
    }
#pragma unroll
    for (int s = 0; s < NWST; ++s) {
      int i = s * 256 + tid;
      if (i < WSLAB) {
        int row = i / OCH, c = i - row * OCH;
        wtmp[s] = wT[(size_t)ic0 * (K * K * OCTOT) + (size_t)row * OCTOT +
                     oc0 + c];
      }
    }
  };
  auto writec = [&](int b) {
#pragma unroll
    for (int s = 0; s < NSTG; ++s) {
      int i = s * 256 + tid;
      if (i < TOT) lds[b][i] = tmp[s];
    }
#pragma unroll
    for (int s = 0; s < NWST; ++s) {
      int i = s * 256 + tid;
      if (i < WSLAB) wlds[b][i] = wtmp[s];
    }
  };

  loadc(0);
  writec(0);
  __syncthreads();

  int cur = 0;
#pragma unroll 1
  for (int ch = 0; ch < NCH; ++ch) {
    if (ch + 1 < NCH) loadc((ch + 1) * CCH);   // issue next-chunk loads early

    const float* L = lds[cur];
    const float* WL = wlds[cur];
#pragma unroll 1
    for (int c = 0; c < CCH; ++c) {
#pragma unroll
      for (int ky = 0; ky < K; ++ky) {
        float vwin[VW];
        const float* vrow = L + (c * RS + r * S + ky) * CS + c0 * S;
#pragma unroll
        for (int q = 0; q < VW / 4; ++q) {
          float4 t = ((const float4*)vrow)[q];
          vwin[4 * q + 0] = t.x; vwin[4 * q + 1] = t.y;
          vwin[4 * q + 2] = t.z; vwin[4 * q + 3] = t.w;
        }
#pragma unroll
        for (int kx = 0; kx < K; ++kx) {
          const float4* w4 =
              (const float4*)(WL + (c * K * K + ky * K + kx) * OCH);
#pragma unroll
          for (int q = 0; q < OCH / 4; ++q) {
            float4 wv = w4[q];
#pragma unroll
            for (int p = 0; p < 4; ++p) {
              acc[p][4 * q + 0] = fmaf(wv.x, vwin[p * S + kx], acc[p][4 * q + 0]);
              acc[p][4 * q + 1] = fmaf(wv.y, vwin[p * S + kx], acc[p][4 * q + 1]);
              acc[p][4 * q + 2] = fmaf(wv.z, vwin[p * S + kx], acc[p][4 * q + 2]);
              acc[p][4 * q + 3] = fmaf(wv.w, vwin[p * S + kx], acc[p][4 * q + 3]);
            }
          }
        }
      }
    }

    if (ch + 1 < NCH) writec(cur ^ 1);
    __syncthreads();
    cur ^= 1;
  }

  const int oh = oh0 + r, ow = ow0 + c0;
#pragma unroll
  for (int oc = 0; oc < OCH; ++oc) {
    float4 o;
    o.x = acc[0][oc]; o.y = acc[1][oc]; o.z = acc[2][oc]; o.w = acc[3][oc];
    if (RELU_OUT) {
      o.x = fmaxf(o.x, 0.f); o.y = fmaxf(o.y, 0.f);
      o.z = fmaxf(o.z, 0.f); o.w = fmaxf(o.w, 0.f);
    }
    *(float4*)(out + ((size_t)(n * OCTOT + oc0 + oc) * OH + oh) * OW + ow) = o;
  }
}

// 1x1 conv (relu on read) + residual add, fp32; weights staged in LDS. (R14)
template<int IC, int OC>
__global__ __launch_bounds__(256) void conv1x1_res(
    const float* __restrict__ in, const float* __restrict__ wT,
    const float* __restrict__ bias, const float* __restrict__ res,
    float* __restrict__ out) {
  __shared__ __align__(16) float wlds[IC * OC];
  for (int i = threadIdx.x; i < IC * OC; i += 256) wlds[i] = wT[i];
  __syncthreads();

  const int pid = blockIdx.x * 256 + threadIdx.x;
  const int n = pid >> 12, px = pid & 4095;
  const float* ip = in + (size_t)n * IC * 4096 + px;
  float acc[OC];
#pragma unroll
  for (int o = 0; o < OC; ++o) acc[o] = bias[o];
#pragma unroll 4
  for (int i = 0; i < IC; ++i) {
    float v = fmaxf(ip[(size_t)i * 4096], 0.f);
    const float4* w4 = (const float4*)(wlds + i * OC);
#pragma unroll
    for (int q = 0; q < OC / 4; ++q) {
      float4 wv = w4[q];
      acc[4 * q + 0] = fmaf(wv.x, v, acc[4 * q + 0]);
      acc[4 * q + 1] = fmaf(wv.y, v, acc[4 * q + 1]);
      acc[4 * q + 2] = fmaf(wv.z, v, acc[4 * q + 2]);
      acc[4 * q + 3] = fmaf(wv.w, v, acc[4 * q + 3]);
    }
  }
  const float* rp = res + (size_t)n * OC * 4096 + px;
  float* op = out + (size_t)n * OC * 4096 + px;
#pragma unroll
  for (int o = 0; o < OC; ++o) op[(size_t)o * 4096] = rp[(size_t)o * 4096] + acc[o];
}

// Fused conv4 + VQ (R14). LDS-staged wT4/e2/emb-chunks; BHWD gather.
__global__ __launch_bounds__(256) void conv4_vq(
    const float* __restrict__ h, const float* __restrict__ wT4,
    const float* __restrict__ b4, const float* __restrict__ emb,
    const float* __restrict__ e2, float* __restrict__ out) {
  __shared__ __align__(16) float wlds[128 * 64];
  __shared__ __align__(16) float elds[64 * 64];
  __shared__ float e2lds[512];

  const int tid = threadIdx.x;
  for (int i = tid; i < 128 * 64; i += 256) wlds[i] = wT4[i];
  for (int i = tid; i < 512; i += 256) e2lds[i] = e2[i];
  __syncthreads();

  const int pid = blockIdx.x * 256 + tid;
  const int n = pid >> 12, px = pid & 4095;
  const float* ip = h + (size_t)n * 128 * 4096 + px;
  float z[64];
#pragma unroll
  for (int d = 0; d < 64; ++d) z[d] = b4[d];
#pragma unroll 2
  for (int i = 0; i < 128; ++i) {
    float v = fmaxf(ip[(size_t)i * 4096], 0.f);
    const float4* w4 = (const float4*)(wlds + i * 64);
#pragma unroll
    for (int q = 0; q < 16; ++q) {
      float4 wv = w4[q];
      z[4 * q + 0] = fmaf(wv.x, v, z[4 * q + 0]);
      z[4 * q + 1] = fmaf(wv.y, v, z[4 * q + 1]);
      z[4 * q + 2] = fmaf(wv.z, v, z[4 * q + 2]);
      z[4 * q + 3] = fmaf(wv.w, v, z[4 * q + 3]);
    }
  }
  float z2 = 0.f;
#pragma unroll
  for (int d = 0; d < 64; ++d) z2 = fmaf(z[d], z[d], z2);

  float best = __builtin_inff();
  int bidx = 0;
  for (int r0 = 0; r0 < 512; r0 += 64) {
    __syncthreads();
    for (int i = tid; i < 64 * 64; i += 256) elds[i] = emb[(size_t)r0 * 64 + i];
    __syncthreads();
#pragma unroll 1
    for (int r = 0; r < 64; ++r) {
      const float4* e4 = (const float4*)(elds + r * 64);
      float p0 = 0.f, p1 = 0.f, p2 = 0.f, p3 = 0.f;
#pragma unroll
      for (int q = 0; q < 16; ++q) {
        float4 ev = e4[q];
        p0 = fmaf(ev.x, z[4 * q + 0], p0);
        p1 = fmaf(ev.y, z[4 * q + 1], p1);
        p2 = fmaf(ev.z, z[4 * q + 2], p2);
        p3 = fmaf(ev.w, z[4 * q + 3], p3);
      }
      float dot = (p0 + p1) + (p2 + p3);
      float dist = (z2 - 2.f * dot) + e2lds[r0 + r];
      if (dist < best) { best = dist; bidx = r0 + r; }
    }
  }

  const float4* eb = (const float4*)(emb + (size_t)bidx * 64);
  float4* op = (float4*)(out + (size_t)pid * 64);
#pragma unroll
  for (int q = 0; q < 16; ++q) op[q] = eb[q];
}

extern "C" void kernel_launch(void* const* d_in, const int* in_sizes, int n_in,
                              void* d_out, int out_size, void* d_ws, size_t ws_size,
                              hipStream_t stream) {
  const float* x    = (const float*)d_in[0];
  const float* w1   = (const float*)d_in[1];
  const float* b1   = (const float*)d_in[2];
  const float* w2   = (const float*)d_in[3];
  const float* b2   = (const float*)d_in[4];
  const float* w3   = (const float*)d_in[5];
  const float* b3   = (const float*)d_in[6];
  const float* r1w1 = (const float*)d_in[7];
  const float* r1b1 = (const float*)d_in[8];
  const float* r1w2 = (const float*)d_in[9];
  const float* r1b2 = (const float*)d_in[10];
  const float* r2w1 = (const float*)d_in[11];
  const float* r2b1 = (const float*)d_in[12];
  const float* r2w2 = (const float*)d_in[13];
  const float* r2b2 = (const float*)d_in[14];
  const float* w4   = (const float*)d_in[15];
  const float* b4   = (const float*)d_in[16];
  const float* emb  = (const float*)d_in[17];

  char* ws = (char*)d_ws;
  float* wT1   = (float*)ws;         // 1024
  float* wT2   = wT1 + 1024;         // 131072
  float* wT3   = wT2 + 131072;       // 147456
  float* wTr1a = wT3 + 147456;       // 36864
  float* wTr1b = wTr1a + 36864;      // 4096
  float* wTr2a = wTr1b + 4096;       // 36864
  float* wTr2b = wTr2a + 36864;      // 4096
  float* wT4   = wTr2b + 4096;       // 8192
  float* e2v   = wT4 + 8192;         // 512

  const size_t WOFF = 2ull << 20;
  const size_t SZ_A = 4194304ull;    // 64ch*128*128*4 (h1/h3/h5)
  const size_t SZ_B = 2097152ull;    // 128ch*64*64*4  (h2/h4)
  const size_t SZ_C = 524288ull;     // 32ch*64*64*4   (t32)
  const size_t PER_IMG = SZ_A + SZ_B + SZ_C;
  int NB = 64;
  while (NB > 1 && WOFF + (size_t)NB * PER_IMG > ws_size) NB >>= 1;

  char* bufs = ws + WOFF;
  float* A  = (float*)bufs;
  float* B_ = (float*)(bufs + (size_t)NB * SZ_A);
  float* C_ = (float*)(bufs + (size_t)NB * (SZ_A + SZ_B));

  auto blk = [](int tot) { return (tot + 255) / 256; };
  repack_k<64> <<<blk(1024),   256, 0, stream>>>(w1,   wT1,   1024);
  repack_k<128><<<blk(131072), 256, 0, stream>>>(w2,   wT2,   131072);
  repack_k<128><<<blk(147456), 256, 0, stream>>>(w3,   wT3,   147456);
  repack_k<32> <<<blk(36864),  256, 0, stream>>>(r1w1, wTr1a, 36864);
  repack_k<128><<<blk(4096),   256, 0, stream>>>(r1w2, wTr1b, 4096);
  repack_k<32> <<<blk(36864),  256, 0, stream>>>(r2w1, wTr2a, 36864);
  repack_k<128><<<blk(4096),   256, 0, stream>>>(r2w2, wTr2b, 4096);
  repack_k<64> <<<blk(8192),   256, 0, stream>>>(w4,   wT4,   8192);
  e2_k<<<2, 256, 0, stream>>>(emb, e2v);

  for (int n0 = 0; n0 < 64; n0 += NB) {
    const int nb = (64 - n0 < NB) ? (64 - n0) : NB;
    const float* xc = x + (size_t)n0 * 65536;               // (nb,1,256,256)
    float* oc = (float*)d_out + (size_t)n0 * 4096 * 64;     // BHWD chunk base

    // conv1: 1px, OC=64 whole (R14 config)
    conv_direct<1, 64, 64, 4, 2, 1, 1, 256, 256, false, true>
        <<<dim3(64, nb), 256, 0, stream>>>(xc, wT1, b1, A);
    // conv2: 4px + async dbuf staging; 4 tiles x 4 slices, CCH=2
    conv_p4db<64, 128, 32, 4, 2, 1, 2, 128, 128, false, true>
        <<<dim3(16, nb), 256, 0, stream>>>(A, wT2, b2, B_);
    // conv3: 4px + async dbuf staging; 4 tiles x 4 slices, CCH=4
    conv_p4db<128, 128, 32, 3, 1, 1, 4, 64, 64, false, false>
        <<<dim3(16, nb), 256, 0, stream>>>(B_, wT3, b3, A);
    // res1: 1px, OC=32 whole, CCH=8 (R14 config)
    conv_direct<128, 32, 32, 3, 1, 1, 8, 64, 64, true, false>
        <<<dim3(16, nb), 256, 0, stream>>>(A, wTr1a, r1b1, C_);
    conv1x1_res<32, 128><<<nb * 16, 256, 0, stream>>>(C_, wTr1b, r1b2, A, B_);
    // res2
    conv_direct<128, 32, 32, 3, 1, 1, 8, 64, 64, true, false>
        <<<dim3(16, nb), 256, 0, stream>>>(B_, wTr2a, r2b1, C_);
    conv1x1_res<32, 128><<<nb * 16, 256, 0, stream>>>(C_, wTr2b, r2b2, B_, A);
    // conv4 + VQ
    conv4_vq<<<nb * 16, 256, 0, stream>>>(A, wT4, b4, emb, e2v, oc);
  }
}